// Round 6
// baseline (455.682 us; speedup 1.0000x reference)
//
#include <hip/hip_runtime.h>
#include <hip/hip_fp16.h>

#define DIM 64
#define K_PASSES 8
#define EPT 16  // elements per thread, phase 1

typedef int          vint4   __attribute__((ext_vector_type(4)));
typedef float        vfloat4 __attribute__((ext_vector_type(4)));
typedef unsigned int vuint4  __attribute__((ext_vector_type(4)));

static __device__ __forceinline__ float2 h2f2(unsigned u) {
    __half2 h = __builtin_bit_cast(__half2, u);
    return __half22float2(h);
}

// Phase 1: esum[g] = (half)(hw[widx[0][g]] + hw[widx[1][g]]), g in [0,total).
// Cache-blocked gather: 32 indices + 32 partials in VGPRs, sweep hw in
// K_PASSES slices sized for per-XCD L2 (12.8MB/8 = 1.6MB). fp16 output halves
// the write traffic and phase-2's read traffic.
__global__ void emb_sum_kernel(const int* __restrict__ widx,
                               const float* __restrict__ hw,
                               __half* __restrict__ esum,
                               long long total /* num_emb*DIM */,
                               int hashed_size) {
    long long base = ((long long)blockIdx.x * blockDim.x + threadIdx.x) * EPT;
    if (base >= total) return;
    if (base + EPT <= total) {
        int idx[2 * EPT];
        const vint4* w0 = (const vint4*)(widx + base);
        const vint4* w1 = (const vint4*)(widx + base + total);
#pragma unroll
        for (int q = 0; q < EPT / 4; ++q) {
            vint4 a = __builtin_nontemporal_load(w0 + q);
            idx[4 * q + 0] = a.x; idx[4 * q + 1] = a.y;
            idx[4 * q + 2] = a.z; idx[4 * q + 3] = a.w;
        }
#pragma unroll
        for (int q = 0; q < EPT / 4; ++q) {
            vint4 b = __builtin_nontemporal_load(w1 + q);
            idx[EPT + 4 * q + 0] = b.x; idx[EPT + 4 * q + 1] = b.y;
            idx[EPT + 4 * q + 2] = b.z; idx[EPT + 4 * q + 3] = b.w;
        }
        float r[2 * EPT];
#pragma unroll
        for (int i = 0; i < 2 * EPT; ++i) r[i] = 0.0f;

        int slice = (hashed_size + K_PASSES - 1) / K_PASSES;
        int lo = 0;
        for (int k = 0; k < K_PASSES; ++k, lo += slice) {
#pragma unroll
            for (int i = 0; i < 2 * EPT; ++i) {
                if ((unsigned)(idx[i] - lo) < (unsigned)slice)
                    r[i] += hw[idx[i]];
            }
        }
        // pack 16 fp32 sums -> 16 halves -> two 16B stores
        unsigned u[EPT / 2];
#pragma unroll
        for (int p = 0; p < EPT / 2; ++p) {
            float s0 = r[2 * p] + r[EPT + 2 * p];
            float s1 = r[2 * p + 1] + r[EPT + 2 * p + 1];
            __half2 h = __halves2half2(__float2half_rn(s0), __float2half_rn(s1));
            u[p] = __builtin_bit_cast(unsigned, h);
        }
        vuint4* o = (vuint4*)(esum + base);
        vuint4 o0 = {u[0], u[1], u[2], u[3]};
        vuint4 o1 = {u[4], u[5], u[6], u[7]};
        o[0] = o0;
        o[1] = o1;
    } else {
        for (long long g = base; g < total; ++g)
            esum[g] = __float2half_rn(hw[widx[g]] + hw[widx[g + total]]);
    }
}

// Phase 2: one wave per bag. 8 token-groups of 8 lanes; each group loads one
// fp16 token row (128B) as uint4 (16B/lane). 8 rows per VMEM instruction.
// fp32 accumulate; butterfly-reduce across groups (lane bits 3,4,5).
__global__ void bag_sum_kernel(const int* __restrict__ x,
                               const int* __restrict__ offsets,
                               const __half* __restrict__ esum,
                               float* __restrict__ out,
                               int num_bags, int total_tokens) {
    int wave = (int)((blockIdx.x * blockDim.x + threadIdx.x) >> 6);
    int lane = threadIdx.x & 63;
    if (wave >= num_bags) return;
    int group = lane >> 3;   // 0..7
    int l8    = lane & 7;    // 0..7
    int start = offsets[wave];
    int end = (wave + 1 < num_bags) ? offsets[wave + 1] : total_tokens;

    float2 acc0 = {0.f, 0.f}, acc1 = {0.f, 0.f}, acc2 = {0.f, 0.f}, acc3 = {0.f, 0.f};
    for (int base = start; base < end; base += 64) {
        int n = end - base;
        if (n > 64) n = 64;
        int xv = (lane < n) ? x[base + lane] : 0;
        int i = 0;
#pragma unroll 2
        for (; i + 8 <= n; i += 8) {
            int e = __shfl(xv, i + group, 64);
            vuint4 v = ((const vuint4*)(esum + (size_t)e * DIM))[l8];
            float2 f0 = h2f2(v.x);
            float2 f1 = h2f2(v.y);
            float2 f2 = h2f2(v.z);
            float2 f3 = h2f2(v.w);
            acc0.x += f0.x; acc0.y += f0.y;
            acc1.x += f1.x; acc1.y += f1.y;
            acc2.x += f2.x; acc2.y += f2.y;
            acc3.x += f3.x; acc3.y += f3.y;
        }
        if (i < n) {
            int r = n - i;
            int src = i + group; if (src > n - 1) src = n - 1;
            int e = __shfl(xv, src, 64);
            vuint4 v = ((const vuint4*)(esum + (size_t)e * DIM))[l8];
            if (group < r) {
                float2 f0 = h2f2(v.x);
                float2 f1 = h2f2(v.y);
                float2 f2 = h2f2(v.z);
                float2 f3 = h2f2(v.w);
                acc0.x += f0.x; acc0.y += f0.y;
                acc1.x += f1.x; acc1.y += f1.y;
                acc2.x += f2.x; acc2.y += f2.y;
                acc3.x += f3.x; acc3.y += f3.y;
            }
        }
    }
    // reduce across the 8 groups: lane bits 3,4,5
#pragma unroll
    for (int m = 8; m <= 32; m <<= 1) {
        acc0.x += __shfl_xor(acc0.x, m, 64); acc0.y += __shfl_xor(acc0.y, m, 64);
        acc1.x += __shfl_xor(acc1.x, m, 64); acc1.y += __shfl_xor(acc1.y, m, 64);
        acc2.x += __shfl_xor(acc2.x, m, 64); acc2.y += __shfl_xor(acc2.y, m, 64);
        acc3.x += __shfl_xor(acc3.x, m, 64); acc3.y += __shfl_xor(acc3.y, m, 64);
    }
    if (lane < 8) {
        vfloat4* orow = (vfloat4*)(out + (size_t)wave * DIM);
        vfloat4 p0 = {acc0.x, acc0.y, acc1.x, acc1.y};
        vfloat4 p1 = {acc2.x, acc2.y, acc3.x, acc3.y};
        orow[l8 * 2]     = p0;
        orow[l8 * 2 + 1] = p1;
    }
}

// Fallback: direct gather (no workspace). One wave per bag.
__global__ void direct_kernel(const int* __restrict__ x,
                              const int* __restrict__ offsets,
                              const float* __restrict__ hw,
                              const int* __restrict__ widx,
                              float* __restrict__ out,
                              int num_bags, int total_tokens,
                              long long emb_total) {
    int wave = (int)((blockIdx.x * blockDim.x + threadIdx.x) >> 6);
    int lane = threadIdx.x & 63;
    if (wave >= num_bags) return;
    int start = offsets[wave];
    int end = (wave + 1 < num_bags) ? offsets[wave + 1] : total_tokens;

    float acc = 0.0f;
    for (int t = start; t < end; ++t) {
        int e = x[t];
        const int* row = widx + (size_t)e * DIM;
        acc += hw[row[lane]] + hw[row[emb_total + lane]];
    }
    out[(size_t)wave * DIM + lane] = acc;
}

extern "C" void kernel_launch(void* const* d_in, const int* in_sizes, int n_in,
                              void* d_out, int out_size, void* d_ws, size_t ws_size,
                              hipStream_t stream) {
    const int*   x       = (const int*)d_in[0];
    const int*   offsets = (const int*)d_in[1];
    const float* hw      = (const float*)d_in[2];
    const int*   widx    = (const int*)d_in[3];
    float*       out     = (float*)d_out;

    int total_tokens = in_sizes[0];
    int num_bags     = in_sizes[1];
    int hashed_size  = in_sizes[2];
    long long widx_elems = in_sizes[3];          // UPD * NUM_EMB * DIM
    long long emb_total  = widx_elems / 2;       // NUM_EMB * DIM

    size_t need = (size_t)emb_total * sizeof(__half);

    if (ws_size >= need) {
        __half* esum = (__half*)d_ws;
        {
            long long nthreads = (emb_total + EPT - 1) / EPT;
            int block = 256;
            long long grid = (nthreads + block - 1) / block;
            emb_sum_kernel<<<(int)grid, block, 0, stream>>>(widx, hw, esum,
                                                            emb_total, hashed_size);
        }
        {
            int block = 256;
            int waves_per_block = block / 64;
            int grid = (num_bags + waves_per_block - 1) / waves_per_block;
            bag_sum_kernel<<<grid, block, 0, stream>>>(x, offsets, esum, out,
                                                       num_bags, total_tokens);
        }
    } else {
        int block = 256;
        int waves_per_block = block / 64;
        int grid = (num_bags + waves_per_block - 1) / waves_per_block;
        direct_kernel<<<grid, block, 0, stream>>>(x, offsets, hw, widx, out,
                                                  num_bags, total_tokens, emb_total);
    }
}

// Round 7
// 328.776 us; speedup vs baseline: 1.3860x; 1.3860x over previous
//
#include <hip/hip_runtime.h>
#include <hip/hip_fp16.h>

#define DIM 64
#define K_PASSES 8
#define EPT 8   // elements per thread, phase 1 (EPT=16 halved occupancy: 185->306us)

typedef int          vint4   __attribute__((ext_vector_type(4)));
typedef float        vfloat4 __attribute__((ext_vector_type(4)));
typedef unsigned int vuint4  __attribute__((ext_vector_type(4)));

static __device__ __forceinline__ float2 h2f2(unsigned u) {
    __half2 h = __builtin_bit_cast(__half2, u);
    return __half22float2(h);
}

// Phase 1: esum[g] = (half)(hw[widx[0][g]] + hw[widx[1][g]]).
// Cache-blocked gather (K_PASSES slices of hw sized for per-XCD L2).
// EPT=8 keeps VGPR ~36 -> high occupancy (phase 1 is concurrency-bound).
__global__ void emb_sum_kernel(const int* __restrict__ widx,
                               const float* __restrict__ hw,
                               __half* __restrict__ esum,
                               long long total /* num_emb*DIM */,
                               int hashed_size) {
    long long base = ((long long)blockIdx.x * blockDim.x + threadIdx.x) * EPT;
    if (base >= total) return;
    if (base + EPT <= total) {
        const vint4* w0 = (const vint4*)(widx + base);
        const vint4* w1 = (const vint4*)(widx + base + total);
        vint4 a0 = __builtin_nontemporal_load(w0);
        vint4 a1 = __builtin_nontemporal_load(w0 + 1);
        vint4 b0 = __builtin_nontemporal_load(w1);
        vint4 b1 = __builtin_nontemporal_load(w1 + 1);
        int idx[16] = {a0.x, a0.y, a0.z, a0.w, a1.x, a1.y, a1.z, a1.w,
                       b0.x, b0.y, b0.z, b0.w, b1.x, b1.y, b1.z, b1.w};
        float r[16];
#pragma unroll
        for (int i = 0; i < 16; ++i) r[i] = 0.0f;

        int slice = (hashed_size + K_PASSES - 1) / K_PASSES;
        int lo = 0;
        for (int k = 0; k < K_PASSES; ++k, lo += slice) {
#pragma unroll
            for (int i = 0; i < 16; ++i) {
                if ((unsigned)(idx[i] - lo) < (unsigned)slice)
                    r[i] += hw[idx[i]];
            }
        }
        // pack 8 fp32 sums -> 8 halves -> one 16B store
        unsigned u[4];
#pragma unroll
        for (int p = 0; p < 4; ++p) {
            float s0 = r[2 * p] + r[8 + 2 * p];
            float s1 = r[2 * p + 1] + r[8 + 2 * p + 1];
            __half2 h = __halves2half2(__float2half_rn(s0), __float2half_rn(s1));
            u[p] = __builtin_bit_cast(unsigned, h);
        }
        vuint4 o0 = {u[0], u[1], u[2], u[3]};
        __builtin_nontemporal_store(o0, (vuint4*)(esum + base));
    } else {
        for (long long g = base; g < total; ++g)
            esum[g] = __float2half_rn(hw[widx[g]] + hw[widx[g + total]]);
    }
}

// Phase 2: one wave per bag; 8 token-groups of 8 lanes, fp16 rows (128B) as
// uint4. For the dominant n==50 case, ALL 7 row-loads are issued back-to-back
// into independent registers before any accumulation -> 7 wave-insts in
// flight (vs 2 with the unrolled loop).
__global__ void __launch_bounds__(256, 8)
bag_sum_kernel(const int* __restrict__ x,
               const int* __restrict__ offsets,
               const __half* __restrict__ esum,
               float* __restrict__ out,
               int num_bags, int total_tokens) {
    int wave = (int)((blockIdx.x * blockDim.x + threadIdx.x) >> 6);
    int lane = threadIdx.x & 63;
    if (wave >= num_bags) return;
    int group = lane >> 3;   // 0..7
    int l8    = lane & 7;    // 0..7
    int start = offsets[wave];
    int end = (wave + 1 < num_bags) ? offsets[wave + 1] : total_tokens;
    int n = end - start;

    float2 acc0 = {0.f, 0.f}, acc1 = {0.f, 0.f}, acc2 = {0.f, 0.f}, acc3 = {0.f, 0.f};

    if (n == 50) {
        int xv = (lane < 50) ? x[start + lane] : 0;
        // pass j covers token j*8+group; j=0..5 full, j=6 has group<2
        int e[7];
#pragma unroll
        for (int j = 0; j < 7; ++j) {
            int src = j * 8 + group; if (src > 49) src = 49;
            e[j] = __shfl(xv, src, 64);
        }
        vuint4 v[7];
#pragma unroll
        for (int j = 0; j < 7; ++j)
            v[j] = ((const vuint4*)(esum + (size_t)e[j] * DIM))[l8];
#pragma unroll
        for (int j = 0; j < 7; ++j) {
            bool ok = (j < 6) || (group < 2);
            if (ok) {
                float2 f0 = h2f2(v[j].x), f1 = h2f2(v[j].y);
                float2 f2 = h2f2(v[j].z), f3 = h2f2(v[j].w);
                acc0.x += f0.x; acc0.y += f0.y;
                acc1.x += f1.x; acc1.y += f1.y;
                acc2.x += f2.x; acc2.y += f2.y;
                acc3.x += f3.x; acc3.y += f3.y;
            }
        }
    } else {
        for (int base = start; base < end; base += 64) {
            int nn = end - base;
            if (nn > 64) nn = 64;
            int xv = (lane < nn) ? x[base + lane] : 0;
            int i = 0;
#pragma unroll 2
            for (; i + 8 <= nn; i += 8) {
                int eo = __shfl(xv, i + group, 64);
                vuint4 v = ((const vuint4*)(esum + (size_t)eo * DIM))[l8];
                float2 f0 = h2f2(v.x), f1 = h2f2(v.y), f2 = h2f2(v.z), f3 = h2f2(v.w);
                acc0.x += f0.x; acc0.y += f0.y;
                acc1.x += f1.x; acc1.y += f1.y;
                acc2.x += f2.x; acc2.y += f2.y;
                acc3.x += f3.x; acc3.y += f3.y;
            }
            if (i < nn) {
                int r = nn - i;
                int src = i + group; if (src > nn - 1) src = nn - 1;
                int eo = __shfl(xv, src, 64);
                vuint4 v = ((const vuint4*)(esum + (size_t)eo * DIM))[l8];
                if (group < r) {
                    float2 f0 = h2f2(v.x), f1 = h2f2(v.y), f2 = h2f2(v.z), f3 = h2f2(v.w);
                    acc0.x += f0.x; acc0.y += f0.y;
                    acc1.x += f1.x; acc1.y += f1.y;
                    acc2.x += f2.x; acc2.y += f2.y;
                    acc3.x += f3.x; acc3.y += f3.y;
                }
            }
        }
    }

    // reduce across the 8 groups: lane bits 3,4,5
#pragma unroll
    for (int m = 8; m <= 32; m <<= 1) {
        acc0.x += __shfl_xor(acc0.x, m, 64); acc0.y += __shfl_xor(acc0.y, m, 64);
        acc1.x += __shfl_xor(acc1.x, m, 64); acc1.y += __shfl_xor(acc1.y, m, 64);
        acc2.x += __shfl_xor(acc2.x, m, 64); acc2.y += __shfl_xor(acc2.y, m, 64);
        acc3.x += __shfl_xor(acc3.x, m, 64); acc3.y += __shfl_xor(acc3.y, m, 64);
    }
    if (lane < 8) {
        vfloat4* orow = (vfloat4*)(out + (size_t)wave * DIM);
        vfloat4 p0 = {acc0.x, acc0.y, acc1.x, acc1.y};
        vfloat4 p1 = {acc2.x, acc2.y, acc3.x, acc3.y};
        orow[l8 * 2]     = p0;
        orow[l8 * 2 + 1] = p1;
    }
}

// Fallback: direct gather (no workspace). One wave per bag.
__global__ void direct_kernel(const int* __restrict__ x,
                              const int* __restrict__ offsets,
                              const float* __restrict__ hw,
                              const int* __restrict__ widx,
                              float* __restrict__ out,
                              int num_bags, int total_tokens,
                              long long emb_total) {
    int wave = (int)((blockIdx.x * blockDim.x + threadIdx.x) >> 6);
    int lane = threadIdx.x & 63;
    if (wave >= num_bags) return;
    int start = offsets[wave];
    int end = (wave + 1 < num_bags) ? offsets[wave + 1] : total_tokens;

    float acc = 0.0f;
    for (int t = start; t < end; ++t) {
        int e = x[t];
        const int* row = widx + (size_t)e * DIM;
        acc += hw[row[lane]] + hw[row[emb_total + lane]];
    }
    out[(size_t)wave * DIM + lane] = acc;
}

extern "C" void kernel_launch(void* const* d_in, const int* in_sizes, int n_in,
                              void* d_out, int out_size, void* d_ws, size_t ws_size,
                              hipStream_t stream) {
    const int*   x       = (const int*)d_in[0];
    const int*   offsets = (const int*)d_in[1];
    const float* hw      = (const float*)d_in[2];
    const int*   widx    = (const int*)d_in[3];
    float*       out     = (float*)d_out;

    int total_tokens = in_sizes[0];
    int num_bags     = in_sizes[1];
    int hashed_size  = in_sizes[2];
    long long widx_elems = in_sizes[3];          // UPD * NUM_EMB * DIM
    long long emb_total  = widx_elems / 2;       // NUM_EMB * DIM

    size_t need = (size_t)emb_total * sizeof(__half);

    if (ws_size >= need) {
        __half* esum = (__half*)d_ws;
        {
            long long nthreads = (emb_total + EPT - 1) / EPT;
            int block = 256;
            long long grid = (nthreads + block - 1) / block;
            emb_sum_kernel<<<(int)grid, block, 0, stream>>>(widx, hw, esum,
                                                            emb_total, hashed_size);
        }
        {
            int block = 256;
            int waves_per_block = block / 64;
            int grid = (num_bags + waves_per_block - 1) / waves_per_block;
            bag_sum_kernel<<<grid, block, 0, stream>>>(x, offsets, esum, out,
                                                       num_bags, total_tokens);
        }
    } else {
        int block = 256;
        int waves_per_block = block / 64;
        int grid = (num_bags + waves_per_block - 1) / waves_per_block;
        direct_kernel<<<grid, block, 0, stream>>>(x, offsets, hw, widx, out,
                                                  num_bags, total_tokens, emb_total);
    }
}